// Round 4
// baseline (55.995 us; speedup 1.0000x reference)
//
#include <hip/hip_runtime.h>

// GMP: y[b,s] = sum_{l=0}^{9} C_l(b,s) * x[b,s-l], zero for s < 20.
// C_l = sum_{k=0}^{3} a[k, 9-l] |x[s-l]|^k
//     + sum_{m=0}^{9} sum_{k=1}^{4} b[k-1,l,m] |x[s-l-1-m]|^k
// All fp32. Input c unused by the reference.
//
// Round-4: T=4 samples/thread (amortizes LDS coefficient broadcasts 4x)
// with a ROLLING power window to avoid round-3's register spill:
//  - power quads kept only for window indices [9-l, 23-l) (14 quads live),
//  - one new quad per l-iteration from a single ds_read_b64,
//  - raw x window not kept (re/im extracted immediately).
// All register indexing compile-time constant (full unroll, rule #20).

constexpr int Kp = 4;
constexpr int Lp = 10;
constexpr int Mp = 10;
constexpr int Dp = Lp + Mp;        // 20
constexpr int BLK = 256;
constexpr int T = 4;               // samples per thread
constexpr int TILE = BLK * T;      // 1024 samples per block
constexpr int HALO = Dp - 1;       // 19
constexpr int S_FIXED = 16384;

__global__ __launch_bounds__(BLK, 2) void gmp_kernel(
    const float* __restrict__ x,   // (B, S, 2)
    const float* __restrict__ a,   // (K, L)
    const float* __restrict__ b,   // (K, L, M)
    float* __restrict__ out,       // (B, S, 2)
    int S)
{
    __shared__ alignas(16) float2 sx[TILE + HALO + 1];  // sx[i] = x[s0 - HALO + i]
    __shared__ float sa[Lp][4];            // sa[l][k] = a[k, Lp-1-l]
    __shared__ float sb[Lp * Mp][4];       // sb[l*Mp+m][k] = b[k, l, m]

    const int t = threadIdx.x;
    const int blocksPerRow = S / TILE;     // 16
    const int brow = blockIdx.x / blocksPerRow;
    const int s0   = (blockIdx.x % blocksPerRow) * TILE;

    // stage coefficients (k contiguous -> one ds_read_b128 per (l[,m]))
    if (t < Lp) {
        #pragma unroll
        for (int k = 0; k < Kp; ++k) sa[t][k] = a[k * Lp + (Lp - 1 - t)];
    }
    if (t >= 64 && t < 64 + Lp * Mp) {
        const int lm = t - 64;
        #pragma unroll
        for (int k = 0; k < Kp; ++k) sb[lm][k] = b[k * Lp * Mp + lm];
    }

    // stage x tile with left halo (sx[0..1042]; sx[1043] intentionally
    // unstaged: it is read by the last thread's float4 but never used)
    const float2* __restrict__ xrow =
        reinterpret_cast<const float2*>(x) + (size_t)brow * S;
    for (int i = t; i < TILE + HALO; i += BLK) {
        const int s = s0 - HALO + i;
        sx[i] = (s >= 0) ? xrow[s] : make_float2(0.f, 0.f);
    }
    __syncthreads();

    // window index i (0..22) <-> tile index lt+i; tap for sample j, delay d
    // has i = HALO + j - d:  a-part (d=l): i = 19+j-l; b-part: i = 18+j-l-m.
    const int lt = t * T;

    float q1[23], q2[23], q3[23], q4[23];  // only [9-l,23) ever live
    float rex[13], imx[13];                // re/im of window i in [10,23)

#define GMP_QUAD(i, vx, vy)                                   \
    {                                                         \
        const float m2_ = (vx) * (vx) + (vy) * (vy);          \
        const float r_  = __builtin_amdgcn_sqrtf(m2_);        \
        q1[(i)] = r_;  q2[(i)] = m2_;                         \
        q3[(i)] = m2_ * r_;  q4[(i)] = m2_ * m2_;             \
    }

    // initial window: quads for i in [9,23), via 8 x ds_read_b128
    {
        const float4* sx4 = reinterpret_cast<const float4*>(sx);
        float2 v[16];                       // v[p] = sx[lt + 8 + p]
        #pragma unroll
        for (int n = 0; n < 8; ++n) {
            const float4 f = sx4[2 * t + 4 + n];   // covers [lt+8, lt+24)
            v[2 * n]     = make_float2(f.x, f.y);
            v[2 * n + 1] = make_float2(f.z, f.w);
        }
        #pragma unroll
        for (int i = 9; i < 23; ++i) GMP_QUAD(i, v[i - 8].x, v[i - 8].y);
        #pragma unroll
        for (int i = 10; i < 23; ++i) { rex[i - 10] = v[i - 8].x; imx[i - 10] = v[i - 8].y; }
    }

    float yr[T] = {0.f, 0.f, 0.f, 0.f};
    float yi[T] = {0.f, 0.f, 0.f, 0.f};

    #pragma unroll
    for (int l = 0; l < Lp; ++l) {
        if (l > 0) {                       // roll window down: new quad at 9-l
            const float2 nv = sx[lt + 9 - l];
            GMP_QUAD(9 - l, nv.x, nv.y);
        }
        const float4 ac = *reinterpret_cast<const float4*>(sa[l]);
        float C[T];
        #pragma unroll
        for (int j = 0; j < T; ++j) {
            const int i = HALO + j - l;                     // 19+j-l
            C[j] = ac.x + ac.y * q1[i] + ac.z * q2[i] + ac.w * q3[i];
        }
        #pragma unroll
        for (int m = 0; m < Mp; ++m) {
            const float4 bc = *reinterpret_cast<const float4*>(sb[l * Mp + m]);
            #pragma unroll
            for (int j = 0; j < T; ++j) {
                const int i = HALO - 1 + j - l - m;         // 18+j-l-m
                C[j] += bc.x * q1[i] + bc.y * q2[i]
                      + bc.z * q3[i] + bc.w * q4[i];
            }
        }
        #pragma unroll
        for (int j = 0; j < T; ++j) {
            const int r = 9 + j - l;                        // rex/imx index
            yr[j] += C[j] * rex[r];
            yi[j] += C[j] * imx[r];
        }
    }
#undef GMP_QUAD

    // masked store: 4 consecutive float2 = 2 float4 stores
    const int sbase = s0 + lt;
    const bool k0 = (sbase + 0) >= Dp, k1 = (sbase + 1) >= Dp;
    const bool k2 = (sbase + 2) >= Dp, k3 = (sbase + 3) >= Dp;
    const float4 o01 = make_float4(k0 ? yr[0] : 0.f, k0 ? yi[0] : 0.f,
                                   k1 ? yr[1] : 0.f, k1 ? yi[1] : 0.f);
    const float4 o23 = make_float4(k2 ? yr[2] : 0.f, k2 ? yi[2] : 0.f,
                                   k3 ? yr[3] : 0.f, k3 ? yi[3] : 0.f);
    float4* o4 = reinterpret_cast<float4*>(out) + ((size_t)brow * S + sbase) / 2;
    o4[0] = o01;
    o4[1] = o23;
}

extern "C" void kernel_launch(void* const* d_in, const int* in_sizes, int n_in,
                              void* d_out, int out_size, void* d_ws, size_t ws_size,
                              hipStream_t stream) {
    const float* x = (const float*)d_in[0];
    const float* a = (const float*)d_in[1];
    const float* b = (const float*)d_in[2];
    // d_in[3] (c) is unused by the reference.
    float* out = (float*)d_out;

    const int S = S_FIXED;
    const int B = in_sizes[0] / (2 * S);
    const int nblocks = B * (S / TILE);

    gmp_kernel<<<dim3(nblocks), dim3(BLK), 0, stream>>>(x, a, b, out, S);
}

// Round 5
// 50.572 us; speedup vs baseline: 1.1072x; 1.1072x over previous
//
#include <hip/hip_runtime.h>

// GMP: y[b,s] = sum_{l=0}^{9} C_l(b,s) * x[b,s-l], zero for s < 20.
// C_l = sum_{k=0}^{3} a[k, 9-l] |x[s-l]|^k
//     + sum_{m=0}^{9} sum_{k=1}^{4} b[k-1,l,m] |x[s-l-1-m]|^k
// All fp32. Input c unused by the reference.
//
// Round-5: T=2 samples/thread. Window of power-quads is only 12 positions
// (48 VGPRs) -- hoist-proof: even if the scheduler lifts every rolling
// ds_read, the live set stays < 128 (round 3/4 spilled because their
// T=4 window + init batch exceeded the budget once hoisted).
// sched_barrier(0) at each l-boundary stops cross-iteration hoisting.
// All register indexing compile-time constant after full unroll.

constexpr int Kp = 4;
constexpr int Lp = 10;
constexpr int Mp = 10;
constexpr int Dp = Lp + Mp;        // 20
constexpr int BLK = 256;
constexpr int T = 2;               // samples per thread
constexpr int TILE = BLK * T;      // 512 samples per block
constexpr int HALO = Dp - 1;       // 19
constexpr int S_FIXED = 16384;

__global__ __launch_bounds__(BLK, 4) void gmp_kernel(
    const float* __restrict__ x,   // (B, S, 2)
    const float* __restrict__ a,   // (K, L)
    const float* __restrict__ b,   // (K, L, M)
    float* __restrict__ out,       // (B, S, 2)
    int S)
{
    __shared__ alignas(16) float2 sx[TILE + HALO + 1];  // sx[i] = x[s0-HALO+i]
    __shared__ float sa[Lp][4];            // sa[l][k] = a[k, Lp-1-l]
    __shared__ float sb[Lp * Mp][4];       // sb[l*Mp+m][k] = b[k, l, m]

    const int t = threadIdx.x;
    const int blocksPerRow = S / TILE;     // 32
    const int brow = blockIdx.x / blocksPerRow;
    const int s0   = (blockIdx.x % blocksPerRow) * TILE;

    // stage coefficients (k contiguous -> one ds_read_b128 broadcast each)
    if (t < Lp) {
        #pragma unroll
        for (int k = 0; k < Kp; ++k) sa[t][k] = a[k * Lp + (Lp - 1 - t)];
    }
    if (t >= 64 && t < 64 + Lp * Mp) {
        const int lm = t - 64;
        #pragma unroll
        for (int k = 0; k < Kp; ++k) sb[lm][k] = b[k * Lp * Mp + lm];
    }

    // stage x tile with left halo (valid indices 0..TILE+HALO-1 = 530)
    const float2* __restrict__ xrow =
        reinterpret_cast<const float2*>(x) + (size_t)brow * S;
    for (int i = t; i < TILE + HALO; i += BLK) {
        const int s = s0 - HALO + i;
        sx[i] = (s >= 0) ? xrow[s] : make_float2(0.f, 0.f);
    }
    __syncthreads();

    // Thread handles samples s0+lt, s0+lt+1 (lt = 2t). Window position
    // w = HALO + j - d, tile index lt + w.  a-part (d=l): w = 19+j-l;
    // b-part (d=l+1+m): w = 18+j-l-m.  Needed at iter l: w in [9-l, 21-l).
    const int lt = 2 * t;

    float q1[21], q2[21], q3[21], q4[21];  // <=12 positions live at a time
    float rex[11], imx[11];                // re/im of window pos r+10

#define GMP_QUAD(i, vx, vy)                                   \
    {                                                         \
        const float m2_ = (vx) * (vx) + (vy) * (vy);          \
        const float r_  = __builtin_amdgcn_sqrtf(m2_);        \
        q1[(i)] = r_;  q2[(i)] = m2_;                         \
        q3[(i)] = m2_ * r_;  q4[(i)] = m2_ * m2_;             \
    }

    // init window: quads for w in [9,21), re/im for w in [10,21),
    // read as 7 float4 covering tile float2 [lt+8, lt+22), consumed
    // immediately (no raw batch kept live).
    {
        const float4* sx4 = reinterpret_cast<const float4*>(sx);
        #pragma unroll
        for (int n = 0; n < 7; ++n) {
            const float4 f = sx4[t + 4 + n];
            const int w0 = 8 + 2 * n, w1 = 9 + 2 * n;
            if (w0 >= 9 && w0 < 21) GMP_QUAD(w0, f.x, f.y);
            if (w1 >= 9 && w1 < 21) GMP_QUAD(w1, f.z, f.w);
            if (w0 >= 10 && w0 < 21) { rex[w0 - 10] = f.x; imx[w0 - 10] = f.y; }
            if (w1 >= 10 && w1 < 21) { rex[w1 - 10] = f.z; imx[w1 - 10] = f.w; }
        }
    }

    float yr0 = 0.f, yi0 = 0.f, yr1 = 0.f, yi1 = 0.f;

    #pragma unroll
    for (int l = 0; l < Lp; ++l) {
        __builtin_amdgcn_sched_barrier(0);
        if (l > 0) {                       // roll: add quad at w = 9-l
            const float2 nv = sx[lt + 9 - l];
            GMP_QUAD(9 - l, nv.x, nv.y);
        }
        const float4 ac = *reinterpret_cast<const float4*>(sa[l]);
        const int wa0 = 19 - l, wa1 = 20 - l;
        float C0 = ac.x + ac.y * q1[wa0] + ac.z * q2[wa0] + ac.w * q3[wa0];
        float C1 = ac.x + ac.y * q1[wa1] + ac.z * q2[wa1] + ac.w * q3[wa1];
        #pragma unroll
        for (int m = 0; m < Mp; ++m) {
            const float4 bc = *reinterpret_cast<const float4*>(sb[l * Mp + m]);
            const int w0 = 18 - l - m, w1 = 19 - l - m;
            C0 += bc.x * q1[w0] + bc.y * q2[w0] + bc.z * q3[w0] + bc.w * q4[w0];
            C1 += bc.x * q1[w1] + bc.y * q2[w1] + bc.z * q3[w1] + bc.w * q4[w1];
        }
        const int r = 9 - l;               // rex index for j=0 (j=1 -> r+1)
        yr0 += C0 * rex[r];     yi0 += C0 * imx[r];
        yr1 += C1 * rex[r + 1]; yi1 += C1 * imx[r + 1];
    }
#undef GMP_QUAD

    // masked store: 2 consecutive float2 = 1 float4 store
    const int sbase = s0 + lt;
    const bool k0 = (sbase + 0) >= Dp, k1 = (sbase + 1) >= Dp;
    const float4 o = make_float4(k0 ? yr0 : 0.f, k0 ? yi0 : 0.f,
                                 k1 ? yr1 : 0.f, k1 ? yi1 : 0.f);
    reinterpret_cast<float4*>(out)[((size_t)brow * S + sbase) / 2] = o;
}

extern "C" void kernel_launch(void* const* d_in, const int* in_sizes, int n_in,
                              void* d_out, int out_size, void* d_ws, size_t ws_size,
                              hipStream_t stream) {
    const float* x = (const float*)d_in[0];
    const float* a = (const float*)d_in[1];
    const float* b = (const float*)d_in[2];
    // d_in[3] (c) is unused by the reference.
    float* out = (float*)d_out;

    const int S = S_FIXED;
    const int B = in_sizes[0] / (2 * S);
    const int nblocks = B * (S / TILE);

    gmp_kernel<<<dim3(nblocks), dim3(BLK), 0, stream>>>(x, a, b, out, S);
}

// Round 6
// 18.171 us; speedup vs baseline: 3.0816x; 2.7831x over previous
//
#include <hip/hip_runtime.h>

// GMP: y[b,s] = sum_{l=0}^{9} C_l(b,s) * x[b,s-l], zero for s < 20.
// C_l = sum_{k=0}^{3} a[k, 9-l] |x[s-l]|^k
//     + sum_{m=0}^{9} sum_{k=1}^{4} b[k-1,l,m] |x[s-l-1-m]|^k
// All fp32. Input c unused by the reference.
//
// Round-6: round-5 math (T=2 samples/thread, rolling 12-quad window,
// LDS float4 coefficient broadcasts) with the register-allocator
// handcuffs removed: NO min-waves launch bound (rounds 3/4/5 all
// spilled because the bound capped VGPRs below the live set; the
// allocator empirically picks half the cap) and NO sched_barrier
// order-pinning. Live set ~95-130 floats -> fits without scratch.

constexpr int Kp = 4;
constexpr int Lp = 10;
constexpr int Mp = 10;
constexpr int Dp = Lp + Mp;        // 20
constexpr int BLK = 256;
constexpr int T = 2;               // samples per thread
constexpr int TILE = BLK * T;      // 512 samples per block
constexpr int HALO = Dp - 1;       // 19
constexpr int S_FIXED = 16384;

__global__ __launch_bounds__(BLK) void gmp_kernel(
    const float* __restrict__ x,   // (B, S, 2)
    const float* __restrict__ a,   // (K, L)
    const float* __restrict__ b,   // (K, L, M)
    float* __restrict__ out,       // (B, S, 2)
    int S)
{
    __shared__ alignas(16) float2 sx[TILE + HALO + 1];  // sx[i] = x[s0-HALO+i]
    __shared__ float sa[Lp][4];            // sa[l][k] = a[k, Lp-1-l]
    __shared__ float sb[Lp * Mp][4];       // sb[l*Mp+m][k] = b[k, l, m]

    const int t = threadIdx.x;
    const int blocksPerRow = S / TILE;     // 32
    const int brow = blockIdx.x / blocksPerRow;
    const int s0   = (blockIdx.x % blocksPerRow) * TILE;

    // stage coefficients (k contiguous -> one ds_read_b128 broadcast each)
    if (t < Lp) {
        #pragma unroll
        for (int k = 0; k < Kp; ++k) sa[t][k] = a[k * Lp + (Lp - 1 - t)];
    }
    if (t >= 64 && t < 64 + Lp * Mp) {
        const int lm = t - 64;
        #pragma unroll
        for (int k = 0; k < Kp; ++k) sb[lm][k] = b[k * Lp * Mp + lm];
    }

    // stage x tile with left halo (valid indices 0..TILE+HALO-1 = 530)
    const float2* __restrict__ xrow =
        reinterpret_cast<const float2*>(x) + (size_t)brow * S;
    for (int i = t; i < TILE + HALO; i += BLK) {
        const int s = s0 - HALO + i;
        sx[i] = (s >= 0) ? xrow[s] : make_float2(0.f, 0.f);
    }
    __syncthreads();

    // Thread handles samples s0+lt, s0+lt+1 (lt = 2t). Window position
    // w = HALO + j - d, tile index lt + w.  a-part (d=l): w = 19+j-l;
    // b-part (d=l+1+m): w = 18+j-l-m.  Needed at iter l: w in [9-l, 21-l).
    const int lt = 2 * t;

    float q1[21], q2[21], q3[21], q4[21];  // <=12 positions live at a time
    float rex[11], imx[11];                // re/im of window pos r+10

#define GMP_QUAD(i, vx, vy)                                   \
    {                                                         \
        const float m2_ = (vx) * (vx) + (vy) * (vy);          \
        const float r_  = __builtin_amdgcn_sqrtf(m2_);        \
        q1[(i)] = r_;  q2[(i)] = m2_;                         \
        q3[(i)] = m2_ * r_;  q4[(i)] = m2_ * m2_;             \
    }

    // init window: quads for w in [9,21), re/im for w in [10,21),
    // read as 7 float4 covering tile float2 [lt+8, lt+22), consumed
    // immediately (no raw batch kept live).
    {
        const float4* sx4 = reinterpret_cast<const float4*>(sx);
        #pragma unroll
        for (int n = 0; n < 7; ++n) {
            const float4 f = sx4[t + 4 + n];
            const int w0 = 8 + 2 * n, w1 = 9 + 2 * n;
            if (w0 >= 9 && w0 < 21) GMP_QUAD(w0, f.x, f.y);
            if (w1 >= 9 && w1 < 21) GMP_QUAD(w1, f.z, f.w);
            if (w0 >= 10 && w0 < 21) { rex[w0 - 10] = f.x; imx[w0 - 10] = f.y; }
            if (w1 >= 10 && w1 < 21) { rex[w1 - 10] = f.z; imx[w1 - 10] = f.w; }
        }
    }

    float yr0 = 0.f, yi0 = 0.f, yr1 = 0.f, yi1 = 0.f;

    #pragma unroll
    for (int l = 0; l < Lp; ++l) {
        if (l > 0) {                       // roll: add quad at w = 9-l
            const float2 nv = sx[lt + 9 - l];
            GMP_QUAD(9 - l, nv.x, nv.y);
        }
        const float4 ac = *reinterpret_cast<const float4*>(sa[l]);
        const int wa0 = 19 - l, wa1 = 20 - l;
        float C0 = ac.x + ac.y * q1[wa0] + ac.z * q2[wa0] + ac.w * q3[wa0];
        float C1 = ac.x + ac.y * q1[wa1] + ac.z * q2[wa1] + ac.w * q3[wa1];
        #pragma unroll
        for (int m = 0; m < Mp; ++m) {
            const float4 bc = *reinterpret_cast<const float4*>(sb[l * Mp + m]);
            const int w0 = 18 - l - m, w1 = 19 - l - m;
            C0 += bc.x * q1[w0] + bc.y * q2[w0] + bc.z * q3[w0] + bc.w * q4[w0];
            C1 += bc.x * q1[w1] + bc.y * q2[w1] + bc.z * q3[w1] + bc.w * q4[w1];
        }
        const int r = 9 - l;               // rex index for j=0 (j=1 -> r+1)
        yr0 += C0 * rex[r];     yi0 += C0 * imx[r];
        yr1 += C1 * rex[r + 1]; yi1 += C1 * imx[r + 1];
    }
#undef GMP_QUAD

    // masked store: 2 consecutive float2 = 1 float4 store
    const int sbase = s0 + lt;
    const bool k0 = (sbase + 0) >= Dp, k1 = (sbase + 1) >= Dp;
    const float4 o = make_float4(k0 ? yr0 : 0.f, k0 ? yi0 : 0.f,
                                 k1 ? yr1 : 0.f, k1 ? yi1 : 0.f);
    reinterpret_cast<float4*>(out)[((size_t)brow * S + sbase) / 2] = o;
}

extern "C" void kernel_launch(void* const* d_in, const int* in_sizes, int n_in,
                              void* d_out, int out_size, void* d_ws, size_t ws_size,
                              hipStream_t stream) {
    const float* x = (const float*)d_in[0];
    const float* a = (const float*)d_in[1];
    const float* b = (const float*)d_in[2];
    // d_in[3] (c) is unused by the reference.
    float* out = (float*)d_out;

    const int S = S_FIXED;
    const int B = in_sizes[0] / (2 * S);
    const int nblocks = B * (S / TILE);

    gmp_kernel<<<dim3(nblocks), dim3(BLK), 0, stream>>>(x, a, b, out, S);
}